// Round 8
// baseline (187.193 us; speedup 1.0000x reference)
//
#include <hip/hip_runtime.h>
#include <hip/hip_bf16.h>

// TripletBatchHardLoss: N=8192, D=256, fp32 embeddings (L2-normalized), int32 labels.
// R23 = DIAGNOSTIC ABLATION ROUND (deliberate, one-off). Five structural hypotheses
// (sync style R18 / wave-independence R20 / persistence R21 / occupancy R22 / LDS-free
// R16) all land 42-45us tile with all pipes <30%. Per the ablate-before-optimize rule,
// this round template-splits the best verified kernel (R18 3-buf) into:
//   V=3 (grid x4): staging skeleton only (DMA + counted vmcnt + barriers)
//   V=1 (grid x2): + ds_read + MFMA (acc kept live via asm sinks, no epilogue)
//   V=0 (grid x1): full real kernel (correct outputs -> passed stays true)
// Grid-scaling (x4/x2) lifts variant dispatch durations above the ~43us fillBuffer
// band so they appear in the top-5 counter table; per-tile time = dur/scale.
// LDS 48KB pins ALL variants at 3 blocks/CU -> resource-fair ablation.
// PREDICTION: t(V3)/4 = 28-35us (skeleton ~70-80% of tile time -> DMA-completion
// latency is the wall -> R24 = register-staged T14 path). Falsifier: t(V3)/4 < 15us
// -> wall is ds_read->MFMA chain or epilogue.

#define NS 8192
#define DD 256
#define NTILE 2080
#define EPS_PD 1e-12f
#define BIGF 1e30f

typedef unsigned short u16;
typedef unsigned int u32;
typedef short short8 __attribute__((ext_vector_type(8)));
typedef float f32x4 __attribute__((ext_vector_type(4)));

typedef const __attribute__((address_space(1))) u32 glb_u32;
typedef __attribute__((address_space(3))) u32 lds_u32;

__device__ __forceinline__ void async16(const void* g, void* l) {
    __builtin_amdgcn_global_load_lds((glb_u32*)g, (lds_u32*)l, 16, 0, 0);
}

// order-preserving float <-> uint key (unsigned compare == float compare)
__device__ __forceinline__ u32 fkey(float f) {
    u32 b = __float_as_uint(f);
    return (b & 0x80000000u) ? ~b : (b | 0x80000000u);
}
__device__ __forceinline__ float unkey(u32 k) {
    u32 b = (k & 0x80000000u) ? (k ^ 0x80000000u) : ~k;
    return __uint_as_float(b);
}

__device__ __forceinline__ u16 f2bf_rne(float f) {
    u32 b = __float_as_uint(f);
    b += 0x7FFFu + ((b >> 16) & 1u);
    return (u16)(b >> 16);
}

// DPP lane-move within 16-lane rows (reduction groups are exactly DPP rows)
template <int CTRL>
__device__ __forceinline__ float dpp_mov(float x) {
    return __int_as_float(
        __builtin_amdgcn_update_dpp(0, __float_as_int(x), CTRL, 0xF, 0xF, true));
}

// ---------------- kernel 1: fp32 -> bf16, row sum-of-squares, init keys ----------------
__global__ __launch_bounds__(256) void prep_kernel(
    const float* __restrict__ e, u16* __restrict__ ebf, float* __restrict__ sq,
    u32* __restrict__ mxk, u32* __restrict__ mnk, float* __restrict__ out) {
    const int tid = blockIdx.x * 256 + threadIdx.x;   // 2048 blocks
    const int row = tid >> 6, t = tid & 63;           // one wave per row
    float4 v = ((const float4*)(e + (size_t)row * DD))[t];
    ushort4 u;
    u.x = f2bf_rne(v.x); u.y = f2bf_rne(v.y); u.z = f2bf_rne(v.z); u.w = f2bf_rne(v.w);
    ((ushort4*)(ebf + (size_t)row * DD))[t] = u;
    float s = v.x * v.x + v.y * v.y + v.z * v.z + v.w * v.w;
    for (int o = 32; o; o >>= 1) s += __shfl_down(s, o);
    if (t == 0) {
        sq[row] = s;
        mxk[row] = 0u;            // sentinel for unsigned max
        mnk[row] = 0xFFFFFFFFu;   // sentinel for unsigned min
        if (row == 0) out[0] = 0.0f;
    }
}

// ---------------- kernel 2: R18 3-buf structure, template-ablated ----------------
template <int V>
__global__ __launch_bounds__(256, 3) void tile_kernel(
    const u16* __restrict__ ebf, const int* __restrict__ labels,
    u32* __restrict__ mxk, u32* __restrict__ mnk) {
    __shared__ __attribute__((aligned(16))) u16 lds_a[3][128 * 32];   // 3 x 8 KB
    __shared__ __attribute__((aligned(16))) u16 lds_b[3][128 * 32];   // 3 x 8 KB

    int t = blockIdx.x;
    if constexpr (V > 0) t = t % NTILE;   // grid-scaled variants repeat the tile space
    int j = (int)((sqrtf(8.0f * (float)t + 1.0f) - 1.0f) * 0.5f);
    while ((j + 1) * (j + 2) / 2 <= t) ++j;
    while (j * (j + 1) / 2 > t) --j;
    const int i = t - j * (j + 1) / 2;
    const int bi = i * 128, bj = j * 128;

    const int tid = threadIdx.x;
    const int lane = tid & 63, wid = tid >> 6;
    const int wm = wid >> 1, wn = wid & 1;
    const int l15 = lane & 15, q = lane >> 4;

    const int s0 = wid * 128 + lane, s1 = s0 + 64;
    const int r0 = s0 >> 2, c0 = (s0 & 3) ^ ((r0 >> 2) & 3);
    const int r1 = s1 >> 2, c1 = (s1 & 3) ^ ((r1 >> 2) & 3);
    const u16* gA0 = ebf + (size_t)(bi + r0) * DD + c0 * 8;
    const u16* gA1 = ebf + (size_t)(bi + r1) * DD + c1 * 8;
    const u16* gB0 = ebf + (size_t)(bj + r0) * DD + c0 * 8;
    const u16* gB1 = ebf + (size_t)(bj + r1) * DD + c1 * 8;
    const int ldst0 = wid * 128 * 8, ldst1 = ldst0 + 64 * 8;

    const int swz = (q ^ (l15 >> 2)) * 8;
    const int offa = (wm * 64 + l15) * 32 + swz;
    const int offb = (wn * 64 + l15) * 32 + swz;

#define ISSUE_TILE(buf, ko)                                   \
    do {                                                      \
        async16(gA0 + (ko), &lds_a[buf][ldst0]);              \
        async16(gA1 + (ko), &lds_a[buf][ldst1]);              \
        async16(gB0 + (ko), &lds_b[buf][ldst0]);              \
        async16(gB1 + (ko), &lds_b[buf][ldst1]);              \
    } while (0)

    ISSUE_TILE(0, 0);
    ISSUE_TILE(1, 32);

    f32x4 acc[4][4] = {};
#pragma unroll
    for (int kt = 0; kt < 8; ++kt) {
        const int cur = kt % 3;
        if (kt < 7)
            asm volatile("s_waitcnt vmcnt(4)\n\ts_barrier" ::: "memory");
        else
            asm volatile("s_waitcnt vmcnt(0)\n\ts_barrier" ::: "memory");
        if (kt < 6) ISSUE_TILE((kt + 2) % 3, (kt + 2) * 32);

        if constexpr (V != 3) {   // V=3: skeleton only (no LDS reads, no MFMA)
            short8 af[4], bfr[4];
#pragma unroll
            for (int mi = 0; mi < 4; ++mi)
                af[mi] = *(const short8*)(&lds_a[cur][offa + mi * 512]);
#pragma unroll
            for (int ni = 0; ni < 4; ++ni)
                bfr[ni] = *(const short8*)(&lds_b[cur][offb + ni * 512]);
#pragma unroll
            for (int mi = 0; mi < 4; ++mi)
#pragma unroll
                for (int ni = 0; ni < 4; ++ni)
                    acc[mi][ni] = __builtin_amdgcn_mfma_f32_16x16x32_bf16(
                        af[mi], bfr[ni], acc[mi][ni], 0, 0, 0);
        }
    }

    if constexpr (V != 0) {
        // keep the K-loop's results live without the epilogue (rule #17: DCE guard)
        if constexpr (V != 3) {
#pragma unroll
            for (int mi = 0; mi < 4; ++mi)
#pragma unroll
                for (int ni = 0; ni < 4; ++ni)
                    asm volatile("" : : "v"(acc[mi][ni]));
        }
        return;
    }

    // ---- epilogue (V=0 only): C/D layout col = lane&15, row = q*4 + reg ----
    int li[4][4];
#pragma unroll
    for (int mi = 0; mi < 4; ++mi) {
        const int4 v = *(const int4*)(labels + bi + wm * 64 + mi * 16 + q * 4);
        li[mi][0] = v.x; li[mi][1] = v.y; li[mi][2] = v.z; li[mi][3] = v.w;
    }
    int lj[4];
#pragma unroll
    for (int ni = 0; ni < 4; ++ni) lj[ni] = labels[bj + wn * 64 + ni * 16 + l15];

    float mxn[4][4], mnp[4][4];
    float mxc[4] = {-BIGF, -BIGF, -BIGF, -BIGF};
    float mnc[4] = {BIGF, BIGF, BIGF, BIGF};
#pragma unroll
    for (int mi = 0; mi < 4; ++mi)
#pragma unroll
        for (int r2 = 0; r2 < 4; ++r2) { mxn[mi][r2] = -BIGF; mnp[mi][r2] = BIGF; }

#pragma unroll
    for (int mi = 0; mi < 4; ++mi)
#pragma unroll
        for (int ni = 0; ni < 4; ++ni) {
            const int l = lj[ni];
#pragma unroll
            for (int r2 = 0; r2 < 4; ++r2) {
                const float d = acc[mi][ni][r2];
                const bool same = (li[mi][r2] == l);
                const float sneg = same ? -BIGF : d;
                const float spos = same ? d : BIGF;
                mxn[mi][r2] = fmaxf(mxn[mi][r2], sneg);
                mnp[mi][r2] = fminf(mnp[mi][r2], spos);
                mxc[ni] = fmaxf(mxc[ni], sneg);
                mnc[ni] = fminf(mnc[ni], spos);
            }
        }

#pragma unroll
    for (int ni = 0; ni < 4; ++ni) {
        mxc[ni] = fmaxf(mxc[ni], __shfl_xor(mxc[ni], 16));
        mnc[ni] = fminf(mnc[ni], __shfl_xor(mnc[ni], 16));
        mxc[ni] = fmaxf(mxc[ni], __shfl_xor(mxc[ni], 32));
        mnc[ni] = fminf(mnc[ni], __shfl_xor(mnc[ni], 32));
    }
#pragma unroll
    for (int mi = 0; mi < 4; ++mi)
#pragma unroll
        for (int r2 = 0; r2 < 4; ++r2) {
            float x = mxn[mi][r2], n = mnp[mi][r2];
            x = fmaxf(x, dpp_mov<0xB1>(x));  n = fminf(n, dpp_mov<0xB1>(n));
            x = fmaxf(x, dpp_mov<0x4E>(x));  n = fminf(n, dpp_mov<0x4E>(n));
            x = fmaxf(x, dpp_mov<0x124>(x)); n = fminf(n, dpp_mov<0x124>(n));
            x = fmaxf(x, dpp_mov<0x128>(x)); n = fminf(n, dpp_mov<0x128>(n));
            mxn[mi][r2] = x; mnp[mi][r2] = n;
        }

    float* red = (float*)&lds_a[0][0];
    if (l15 == 0) {
#pragma unroll
        for (int mi = 0; mi < 4; ++mi)
#pragma unroll
            for (int r2 = 0; r2 < 4; ++r2) {
                const int rl = wm * 64 + mi * 16 + q * 4 + r2;
                red[rl * 2 + wn] = mxn[mi][r2];
                red[256 + rl * 2 + wn] = mnp[mi][r2];
            }
    }
    if (q == 0) {
#pragma unroll
        for (int ni = 0; ni < 4; ++ni) {
            const int cl = wn * 64 + ni * 16 + l15;
            red[512 + cl * 2 + wm] = mxc[ni];
            red[768 + cl * 2 + wm] = mnc[ni];
        }
    }
    __syncthreads();
    if (tid < 128) {
        const float mx = fmaxf(red[tid * 2], red[tid * 2 + 1]);
        const float mn = fminf(red[256 + tid * 2], red[256 + tid * 2 + 1]);
        atomicMax(&mxk[bi + tid], fkey(mx));
        atomicMin(&mnk[bi + tid], fkey(mn));
    } else {
        const int c = tid - 128;
        const float mx = fmaxf(red[512 + c * 2], red[512 + c * 2 + 1]);
        const float mn = fminf(red[768 + c * 2], red[768 + c * 2 + 1]);
        atomicMax(&mxk[bj + c], fkey(mx));
        atomicMin(&mnk[bj + c], fkey(mn));
    }
}

// ---------------- kernel 3: per-row loss + mean ----------------
__global__ __launch_bounds__(256) void finalize_kernel(
    const u32* __restrict__ mxk, const u32* __restrict__ mnk,
    const float* __restrict__ sq, float* __restrict__ out) {
    const int i = blockIdx.x * 256 + threadIdx.x;
    const float s = sq[i] + 1.0f;   // sq_i + sq_j, sq_j = 1 +- 1e-7
    const float hn = sqrtf(fmaxf(fmaf(-2.0f, unkey(mxk[i]), s), EPS_PD));
    const float hp = sqrtf(fmaxf(fmaf(-2.0f, unkey(mnk[i]), s), EPS_PD));
    float loss = fmaxf(hp - hn + 1.0f, 0.0f);
    for (int o = 32; o; o >>= 1) loss += __shfl_down(loss, o);
    __shared__ float wsum[4];
    const int lane = threadIdx.x & 63, w = threadIdx.x >> 6;
    if (lane == 0) wsum[w] = loss;
    __syncthreads();
    if (threadIdx.x == 0)
        atomicAdd(out, (wsum[0] + wsum[1] + wsum[2] + wsum[3]) * (1.0f / NS));
}

extern "C" void kernel_launch(void* const* d_in, const int* in_sizes, int n_in,
                              void* d_out, int out_size, void* d_ws, size_t ws_size,
                              hipStream_t stream) {
    const int* labels = (const int*)d_in[0];
    const float* emb = (const float*)d_in[1];
    float* out = (float*)d_out;

    char* ws = (char*)d_ws;
    u16* ebf = (u16*)ws;                                     // 4 MB
    float* sq = (float*)(ws + (size_t)NS * DD * 2);          // 32 KB
    u32* mxk = (u32*)(ws + (size_t)NS * DD * 2 + NS * 4);
    u32* mnk = mxk + NS;

    prep_kernel<<<NS * DD / 4 / 256, 256, 0, stream>>>(emb, ebf, sq, mxk, mnk, out);
    // diagnostic dispatches (write nothing; grid-scaled above the fill band)
    tile_kernel<3><<<NTILE * 4, 256, 0, stream>>>(ebf, labels, mxk, mnk);
    tile_kernel<1><<<NTILE * 2, 256, 0, stream>>>(ebf, labels, mxk, mnk);
    // real kernel
    tile_kernel<0><<<NTILE, 256, 0, stream>>>(ebf, labels, mxk, mnk);
    finalize_kernel<<<NS / 256, 256, 0, stream>>>(mxk, mnk, sq, out);
}

// Round 9
// 104.906 us; speedup vs baseline: 1.7844x; 1.7844x over previous
//
#include <hip/hip_runtime.h>
#include <hip/hip_bf16.h>

// TripletBatchHardLoss: N=8192, D=256, fp32 embeddings (L2-normalized), int32 labels.
// Normalized -> pdist monotone DECREASING in dot:
//   hard_negative = max dot over negs, hard_positive = min dot over poss (diag dot~1 safe).
// R24 = 256x256 DEEP-TILE port (guide's T3+T4 regime). R23 ablation: skeleton 14.6us
// (34%), ds+MFMA <=14.5, epilogue >=13.5 -- three ~equal serialized thirds per tiny
// 8-step tile = the documented 2-phase stall signature (m233: 72% overhead). Remedy is
// depth, not sync style: 4x compute per block so fill/sync/epilogue amortize.
//   - 528 triangular 256-tiles, 512 thr (8 waves, 2M x 4N), per-wave 128x64, acc[8][4].
//   - K = 4 K-tiles of BK=64, dbuf LDS 2x(32+32)KB = 128KB, 1 block/CU.
//   - Staging: 8 DMAs/wave/K-tile (A:4, B:4), issued TWO K-tiles ahead at the tail
//     barrier of kt -> vmcnt(8) waits target ~1300-cyc-old loads; only kt3 drains to 0.
//     7 barriers/block total (R15: 16 barriers for 1/4 the output).
//   - WAR: ISSUE(kt+2 -> buf kt&1) sits after a trailing barrier = all waves' kt reads
//     of that buffer retired. Prologue fills buf0/buf1 (untouched). Per-wave vmcnt
//     drain-then-barrier publishes all 64 block-wide DMAs (each wave drains its own 8).
//   - 8-chunk/row XOR swizzle (c ^ (row&7)), same family as the verified 4-chunk one;
//     B-frags held for the whole K-tile (8 short8), A-frags read per 2-mi phase.
//   - Epilogue once per 256-tile: verified m89 C/D layout, mask loop, DPP/shfl
//     reductions, 12KB LDS combine overlaying sA[0] (last read kt2; kt3 top barrier
//     fences), 4 atomic instrs/wave.
// VGPR: acc 128 (AGPR) + bfr 32 + af 16 + addr/epilogue ~100 ~ 240 unified < 256 cap
// of launch_bounds(512,2). XCD-bijective swizzle (528 = 8*66).
// No __threadfence in wide kernels (R11: per-block fence = per-XCD L2 writeback, +130 us).

#define NS 8192
#define DD 256
#define NT 528
#define EPS_PD 1e-12f
#define BIGF 1e30f

typedef unsigned short u16;
typedef unsigned int u32;
typedef short short8 __attribute__((ext_vector_type(8)));
typedef float f32x4 __attribute__((ext_vector_type(4)));

typedef const __attribute__((address_space(1))) u32 glb_u32;
typedef __attribute__((address_space(3))) u32 lds_u32;

__device__ __forceinline__ void async16(const void* g, void* l) {
    __builtin_amdgcn_global_load_lds((glb_u32*)g, (lds_u32*)l, 16, 0, 0);
}

// order-preserving float <-> uint key (unsigned compare == float compare)
__device__ __forceinline__ u32 fkey(float f) {
    u32 b = __float_as_uint(f);
    return (b & 0x80000000u) ? ~b : (b | 0x80000000u);
}
__device__ __forceinline__ float unkey(u32 k) {
    u32 b = (k & 0x80000000u) ? (k ^ 0x80000000u) : ~k;
    return __uint_as_float(b);
}

__device__ __forceinline__ u16 f2bf_rne(float f) {
    u32 b = __float_as_uint(f);
    b += 0x7FFFu + ((b >> 16) & 1u);
    return (u16)(b >> 16);
}

// DPP lane-move within 16-lane rows (reduction groups are exactly DPP rows)
template <int CTRL>
__device__ __forceinline__ float dpp_mov(float x) {
    return __int_as_float(
        __builtin_amdgcn_update_dpp(0, __float_as_int(x), CTRL, 0xF, 0xF, true));
}

// ---------------- kernel 1: fp32 -> bf16, row sum-of-squares, init keys ----------------
__global__ __launch_bounds__(256) void prep_kernel(
    const float* __restrict__ e, u16* __restrict__ ebf, float* __restrict__ sq,
    u32* __restrict__ mxk, u32* __restrict__ mnk, float* __restrict__ out) {
    const int tid = blockIdx.x * 256 + threadIdx.x;   // 2048 blocks
    const int row = tid >> 6, t = tid & 63;           // one wave per row
    float4 v = ((const float4*)(e + (size_t)row * DD))[t];
    ushort4 u;
    u.x = f2bf_rne(v.x); u.y = f2bf_rne(v.y); u.z = f2bf_rne(v.z); u.w = f2bf_rne(v.w);
    ((ushort4*)(ebf + (size_t)row * DD))[t] = u;
    float s = v.x * v.x + v.y * v.y + v.z * v.z + v.w * v.w;
    for (int o = 32; o; o >>= 1) s += __shfl_down(s, o);
    if (t == 0) {
        sq[row] = s;
        mxk[row] = 0u;            // sentinel for unsigned max
        mnk[row] = 0xFFFFFFFFu;   // sentinel for unsigned min
        if (row == 0) out[0] = 0.0f;
    }
}

// ------- kernel 2: 256x256 deep-tile dot-GEMM + two-sided masked reduction ----------
__global__ __launch_bounds__(512, 2) void tile_kernel(
    const u16* __restrict__ ebf, const int* __restrict__ labels,
    u32* __restrict__ mxk, u32* __restrict__ mnk) {
    // per K-tile: A = 256 rows x 64 k (2048 16B-slots, 32KB), B same.
    // chunk (row, c) stored at slot row*8 + (c ^ (row&7)).
    __shared__ __attribute__((aligned(16))) u16 sA[2][16384];   // 2 x 32 KB
    __shared__ __attribute__((aligned(16))) u16 sB[2][16384];   // 2 x 32 KB

    // XCD-bijective swizzle (528 = 8*66)
    const int b = blockIdx.x;
    const int t = (b & 7) * 66 + (b >> 3);

    // decode linear triangle index -> (i <= j) over 32 groups of 256
    int j = (int)((sqrtf(8.0f * (float)t + 1.0f) - 1.0f) * 0.5f);
    while ((j + 1) * (j + 2) / 2 <= t) ++j;
    while (j * (j + 1) / 2 > t) --j;
    const int i = t - j * (j + 1) / 2;
    const int bi = i * 256, bj = j * 256;

    const int tid = threadIdx.x;
    const int lane = tid & 63, wid = tid >> 6;        // 8 waves
    const int wm = wid >> 2, wn = wid & 3;            // wave tile: rows wm*128+, cols wn*64+
    const int l15 = lane & 15, q = lane >> 4;

    // staging: wave wid owns slots [wid*256, +256) of each 2048-slot tile (4 DMAs each
    // for A and B). slot s: row = s>>3, stored chunk cs = s&7 -> data chunk c = cs^(row&7).
    const u16* gA[4];
    const u16* gB[4];
#pragma unroll
    for (int p = 0; p < 4; ++p) {
        const int s = wid * 256 + p * 64 + lane;
        const int r = s >> 3, c = (s & 7) ^ (r & 7);
        gA[p] = ebf + (size_t)(bi + r) * DD + c * 8;
        gB[p] = ebf + (size_t)(bj + r) * DD + c * 8;
    }
    const int adst = wid * 2048;   // u16 offset of wave's slot region (256 slots * 8)

    // frag-read offsets (u16): row stride 64; want chunk (ks*4+q) of row ->
    // slot row*8 + ((ks*4+q) ^ (row&7)); row&7 == l15&7 (wave/mi/ni bases are mult of 8/16)
    const int e7 = l15 & 7;
    const int cb0 = (q ^ e7) * 8;             // ks=0 chunk offset (u16)
    const int cb1 = ((4 + q) ^ e7) * 8;       // ks=1
    const int rowA = (wm * 128 + l15) * 64;   // + mi*1024
    const int rowB = (wn * 64 + l15) * 64;    // + ni*1024

#define ISSUE_TILE(buf, ko)                                   \
    do {                                                      \
        async16(gA[0] + (ko), &sA[buf][adst]);                \
        async16(gA[1] + (ko), &sA[buf][adst + 512]);          \
        async16(gA[2] + (ko), &sA[buf][adst + 1024]);         \
        async16(gA[3] + (ko), &sA[buf][adst + 1536]);         \
        async16(gB[0] + (ko), &sB[buf][adst]);                \
        async16(gB[1] + (ko), &sB[buf][adst + 512]);          \
        async16(gB[2] + (ko), &sB[buf][adst + 1024]);         \
        async16(gB[3] + (ko), &sB[buf][adst + 1536]);         \
    } while (0)

    // prologue: K-tiles 0,1 into bufs 0,1 (16 DMAs in flight per wave; bufs untouched)
    ISSUE_TILE(0, 0);
    ISSUE_TILE(1, 64);

    f32x4 acc[8][4] = {};
#pragma unroll
    for (int kt = 0; kt < 4; ++kt) {
        const int d = kt & 1;   // static after full unroll
        // drain own kt-batch (8, issued 2 K-tiles ago), keep kt+1's 8 in flight
        if (kt < 3)
            asm volatile("s_waitcnt vmcnt(8)\n\ts_barrier" ::: "memory");
        else
            asm volatile("s_waitcnt vmcnt(0)\n\ts_barrier" ::: "memory");

        // B-frags for the whole K-tile (wave's 64 cols): 8 x ds_read_b128
        short8 bfr[4][2];
#pragma unroll
        for (int ni = 0; ni < 4; ++ni) {
            bfr[ni][0] = *(const short8*)(&sB[d][rowB + ni * 1024 + cb0]);
            bfr[ni][1] = *(const short8*)(&sB[d][rowB + ni * 1024 + cb1]);
        }
        // 4 phases: mi-pair {2p, 2p+1} x all ni x 2 K-steps = 16 MFMA per phase
#pragma unroll
        for (int ph = 0; ph < 4; ++ph) {
            const int m0 = 2 * ph, m1 = 2 * ph + 1;
            const short8 a00 = *(const short8*)(&sA[d][rowA + m0 * 1024 + cb0]);
            const short8 a01 = *(const short8*)(&sA[d][rowA + m0 * 1024 + cb1]);
            const short8 a10 = *(const short8*)(&sA[d][rowA + m1 * 1024 + cb0]);
            const short8 a11 = *(const short8*)(&sA[d][rowA + m1 * 1024 + cb1]);
#pragma unroll
            for (int ni = 0; ni < 4; ++ni) {
                acc[m0][ni] = __builtin_amdgcn_mfma_f32_16x16x32_bf16(
                    a00, bfr[ni][0], acc[m0][ni], 0, 0, 0);
                acc[m0][ni] = __builtin_amdgcn_mfma_f32_16x16x32_bf16(
                    a01, bfr[ni][1], acc[m0][ni], 0, 0, 0);
                acc[m1][ni] = __builtin_amdgcn_mfma_f32_16x16x32_bf16(
                    a10, bfr[ni][0], acc[m1][ni], 0, 0, 0);
                acc[m1][ni] = __builtin_amdgcn_mfma_f32_16x16x32_bf16(
                    a11, bfr[ni][1], acc[m1][ni], 0, 0, 0);
            }
        }
        if (kt < 2) {
            // WAR guard: all waves done reading buf d before kt+2's DMAs clobber it
            asm volatile("s_barrier" ::: "memory");
            ISSUE_TILE(d, (kt + 2) * 64);
        }
    }

    // ---- epilogue: C/D layout col = lane&15, row = q*4 + reg (m89-verified) ----
    // output rows bi + wm*128 + mi*16 + q*4 + r2; cols bj + wn*64 + ni*16 + l15
    int li[8][4];
#pragma unroll
    for (int mi = 0; mi < 8; ++mi) {
        const int4 v = *(const int4*)(labels + bi + wm * 128 + mi * 16 + q * 4);
        li[mi][0] = v.x; li[mi][1] = v.y; li[mi][2] = v.z; li[mi][3] = v.w;
    }
    int lj[4];
#pragma unroll
    for (int ni = 0; ni < 4; ++ni) lj[ni] = labels[bj + wn * 64 + ni * 16 + l15];

    float mxn[8][4], mnp[8][4];                        // row-side per (mi, r)
    float mxc[4] = {-BIGF, -BIGF, -BIGF, -BIGF};       // col-side per ni
    float mnc[4] = {BIGF, BIGF, BIGF, BIGF};
#pragma unroll
    for (int mi = 0; mi < 8; ++mi)
#pragma unroll
        for (int r2 = 0; r2 < 4; ++r2) { mxn[mi][r2] = -BIGF; mnp[mi][r2] = BIGF; }

#pragma unroll
    for (int mi = 0; mi < 8; ++mi)
#pragma unroll
        for (int ni = 0; ni < 4; ++ni) {
            const int l = lj[ni];
#pragma unroll
            for (int r2 = 0; r2 < 4; ++r2) {
                const float d = acc[mi][ni][r2];
                const bool same = (li[mi][r2] == l);
                const float sneg = same ? -BIGF : d;
                const float spos = same ? d : BIGF;
                mxn[mi][r2] = fmaxf(mxn[mi][r2], sneg);
                mnp[mi][r2] = fminf(mnp[mi][r2], spos);
                mxc[ni] = fmaxf(mxc[ni], sneg);
                mnc[ni] = fminf(mnc[ni], spos);
            }
        }

    // col-side: reduce over q (lanes l15, +16, +32, +48) via shfl_xor 16/32
#pragma unroll
    for (int ni = 0; ni < 4; ++ni) {
        mxc[ni] = fmaxf(mxc[ni], __shfl_xor(mxc[ni], 16));
        mnc[ni] = fminf(mnc[ni], __shfl_xor(mnc[ni], 16));
        mxc[ni] = fmaxf(mxc[ni], __shfl_xor(mxc[ni], 32));
        mnc[ni] = fminf(mnc[ni], __shfl_xor(mnc[ni], 32));
    }
    // row-side: 16-lane DPP reduction (xor1, xor2, ror4, ror8)
#pragma unroll
    for (int mi = 0; mi < 8; ++mi)
#pragma unroll
        for (int r2 = 0; r2 < 4; ++r2) {
            float x = mxn[mi][r2], n = mnp[mi][r2];
            x = fmaxf(x, dpp_mov<0xB1>(x));  n = fminf(n, dpp_mov<0xB1>(n));
            x = fmaxf(x, dpp_mov<0x4E>(x));  n = fminf(n, dpp_mov<0x4E>(n));
            x = fmaxf(x, dpp_mov<0x124>(x)); n = fminf(n, dpp_mov<0x124>(n));
            x = fmaxf(x, dpp_mov<0x128>(x)); n = fminf(n, dpp_mov<0x128>(n));
            mxn[mi][r2] = x; mnp[mi][r2] = n;
        }

    // ---- block-level LDS combine -> 4 atomic wave-instrs per wave ----
    // scratch overlays sA[0] (12KB of 32KB; buf0 last read at kt2, kt3's top barrier
    // fences all waves past it; kt3 reads buf1 only).
    // Layout (floats): [0..1023] rowmax[row][wn], [1024..2047] rowmin,
    // [2048..2559] colmax[col][wm], [2560..3071] colmin.
    float* red = (float*)&sA[0][0];
    if (l15 == 0) {
#pragma unroll
        for (int mi = 0; mi < 8; ++mi)
#pragma unroll
            for (int r2 = 0; r2 < 4; ++r2) {
                const int rl = wm * 128 + mi * 16 + q * 4 + r2;
                red[rl * 4 + wn] = mxn[mi][r2];
                red[1024 + rl * 4 + wn] = mnp[mi][r2];
            }
    }
    if (q == 0) {
#pragma unroll
        for (int ni = 0; ni < 4; ++ni) {
            const int cl = wn * 64 + ni * 16 + l15;
            red[2048 + cl * 2 + wm] = mxc[ni];
            red[2560 + cl * 2 + wm] = mnc[ni];
        }
    }
    __syncthreads();
    if (tid < 256) {
        const float4 a = *(const float4*)&red[tid * 4];
        const float4 bm = *(const float4*)&red[1024 + tid * 4];
        const float mx = fmaxf(fmaxf(a.x, a.y), fmaxf(a.z, a.w));
        const float mn = fminf(fminf(bm.x, bm.y), fminf(bm.z, bm.w));
        atomicMax(&mxk[bi + tid], fkey(mx));
        atomicMin(&mnk[bi + tid], fkey(mn));
    } else {
        const int c = tid - 256;
        const float mx = fmaxf(red[2048 + c * 2], red[2048 + c * 2 + 1]);
        const float mn = fminf(red[2560 + c * 2], red[2560 + c * 2 + 1]);
        atomicMax(&mxk[bj + c], fkey(mx));
        atomicMin(&mnk[bj + c], fkey(mn));
    }
}

// ---------------- kernel 3: per-row loss + mean ----------------
__global__ __launch_bounds__(256) void finalize_kernel(
    const u32* __restrict__ mxk, const u32* __restrict__ mnk,
    const float* __restrict__ sq, float* __restrict__ out) {
    const int i = blockIdx.x * 256 + threadIdx.x;
    const float s = sq[i] + 1.0f;   // sq_i + sq_j, sq_j = 1 +- 1e-7
    const float hn = sqrtf(fmaxf(fmaf(-2.0f, unkey(mxk[i]), s), EPS_PD));
    const float hp = sqrtf(fmaxf(fmaf(-2.0f, unkey(mnk[i]), s), EPS_PD));
    float loss = fmaxf(hp - hn + 1.0f, 0.0f);
    for (int o = 32; o; o >>= 1) loss += __shfl_down(loss, o);
    __shared__ float wsum[4];
    const int lane = threadIdx.x & 63, w = threadIdx.x >> 6;
    if (lane == 0) wsum[w] = loss;
    __syncthreads();
    if (threadIdx.x == 0)
        atomicAdd(out, (wsum[0] + wsum[1] + wsum[2] + wsum[3]) * (1.0f / NS));
}

extern "C" void kernel_launch(void* const* d_in, const int* in_sizes, int n_in,
                              void* d_out, int out_size, void* d_ws, size_t ws_size,
                              hipStream_t stream) {
    const int* labels = (const int*)d_in[0];
    const float* emb = (const float*)d_in[1];
    float* out = (float*)d_out;

    char* ws = (char*)d_ws;
    u16* ebf = (u16*)ws;                                     // 4 MB
    float* sq = (float*)(ws + (size_t)NS * DD * 2);          // 32 KB
    u32* mxk = (u32*)(ws + (size_t)NS * DD * 2 + NS * 4);
    u32* mnk = mxk + NS;

    prep_kernel<<<NS * DD / 4 / 256, 256, 0, stream>>>(emb, ebf, sq, mxk, mnk, out);
    tile_kernel<<<NT, 512, 0, stream>>>(ebf, labels, mxk, mnk);
    finalize_kernel<<<NS / 256, 256, 0, stream>>>(mxk, mnk, sq, out);
}